// Round 16
// baseline (321.332 us; speedup 1.0000x reference)
//
#include <hip/hip_runtime.h>
#include <hip/hip_fp8.h>
#include <stdint.h>

#define D 256
#define CAP 64  // bucket capacity per node (= wave width; Poisson(16) overflow ~impossible)

typedef __attribute__((ext_vector_type(8))) short short8;
typedef __attribute__((ext_vector_type(4))) float f32x4;

// swizzled LDS offset (in shorts) of 16B chunk c (0..15) within 128-k row n
#define SW2(n, c) (((n) << 7) + ((((c) ^ ((n) & 7))) << 3))

__device__ inline unsigned short f2bf(float f) {
    uint32_t u = __builtin_bit_cast(uint32_t, f);
    uint32_t r = (u + 0x7FFFu + ((u >> 16) & 1u)) >> 16;  // RNE
    return (unsigned short)r;
}

__device__ inline float bf2f(unsigned short b) {
    return __builtin_bit_cast(float, (uint32_t)b << 16);
}

// 4 packed OCP e4m3 -> 4 floats (HW cvt)
__device__ inline f32x4 fp8x4_to_f32(uint32_t v) {
    __hip_fp8x4_e4m3 a;
    a.__x = v;
    float4 f = (float4)a;
    return (f32x4){f.x, f.y, f.z, f.w};
}

__device__ inline uint8_t f32_to_fp8(float f) {
    __hip_fp8_e4m3 q(f);
    return (uint8_t)q.__x;
}

__device__ __forceinline__ void fill_body(int fid,
                                          const int* __restrict__ src,
                                          const int* __restrict__ dst,
                                          int* __restrict__ cur,
                                          int* __restrict__ ewi, int ne) {
    int i = (fid * 256 + threadIdx.x) * 4;
    if (i + 4 <= ne) {
        int4 s4 = *reinterpret_cast<const int4*>(src + i);
        int4 d4 = *reinterpret_cast<const int4*>(dst + i);
        int p;
        p = atomicAdd(&cur[d4.x], 1);
        if (p < CAP) ewi[d4.x * CAP + p] = s4.x;
        p = atomicAdd(&cur[d4.y], 1);
        if (p < CAP) ewi[d4.y * CAP + p] = s4.y;
        p = atomicAdd(&cur[d4.z], 1);
        if (p < CAP) ewi[d4.z * CAP + p] = s4.z;
        p = atomicAdd(&cur[d4.w], 1);
        if (p < CAP) ewi[d4.w * CAP + p] = s4.w;
    } else {
        for (int j = i; j < ne; ++j) {
            int s = src[j], d = dst[j];
            int p = atomicAdd(&cur[d], 1);
            if (p < CAP) ewi[d * CAP + p] = s;
        }
    }
}

// fused prep+fill: [0, nfill) bucket fill (latency-bound, starts first);
// [nfill, nfill+nf2b) cast x->bf16; [.., +512) W1,W2 transpose+cast.
// cur must be pre-zeroed (hipMemsetAsync).
__global__ __launch_bounds__(256) void k_prepfill(const int* __restrict__ src,
                                                  const int* __restrict__ dst,
                                                  int* __restrict__ cur,
                                                  int* __restrict__ ewi, int ne,
                                                  const float* __restrict__ x,
                                                  unsigned short* __restrict__ xb, int n8,
                                                  const float* __restrict__ W1,
                                                  const float* __restrict__ W2,
                                                  unsigned short* __restrict__ Wt1,
                                                  unsigned short* __restrict__ Wt2,
                                                  int nfill, int nf2b) {
    int b = blockIdx.x, t = threadIdx.x;
    if (b < nfill) {
        fill_body(b, src, dst, cur, ewi, ne);
    } else if (b < nfill + nf2b) {
        int i = (b - nfill) * 256 + t;
        if (i < n8) {
            f32x4 v0 = ((const f32x4*)x)[i * 2];
            f32x4 v1 = ((const f32x4*)x)[i * 2 + 1];
            short8 o;
            o[0] = (short)f2bf(v0.x); o[1] = (short)f2bf(v0.y);
            o[2] = (short)f2bf(v0.z); o[3] = (short)f2bf(v0.w);
            o[4] = (short)f2bf(v1.x); o[5] = (short)f2bf(v1.y);
            o[6] = (short)f2bf(v1.z); o[7] = (short)f2bf(v1.w);
            ((short8*)xb)[i] = o;
        }
    } else {
        int idx = (b - nfill - nf2b) * 256 + t;   // [0, 131072)
        int w = idx >> 16;                        // 0 -> W1, 1 -> W2
        int r = idx & 65535;
        int n = r >> 8, k = r & 255;
        const float* W = w ? W2 : W1;
        unsigned short* Wt = w ? Wt2 : Wt1;
        Wt[n * 256 + k] = f2bf(W[k * 256 + n]);
    }
}

// 128x128 tile gemm; B staged in LDS in TWO 128-k halves (32 KB), A in regs.
// 4 waves 2x2; per wave 4x4 MFMA frags. C written as OCP e4m3 fp8.
__global__ __launch_bounds__(256, 2) void k_gemm(const unsigned short* __restrict__ A,
                                                 const unsigned short* __restrict__ Bt,
                                                 uint8_t* __restrict__ Cb, int M) {
    __shared__ unsigned short sm[16384];  // 32 KB
    int gid = blockIdx.x;
    int t = threadIdx.x;
    int wave = t >> 6, lane = t & 63;
    int quad = lane >> 4, l16 = lane & 15;
    int mr = wave >> 1, nc = wave & 1;
    int bm = (gid >> 1) * 128;
    int bn = (gid & 1) * 128;

    // preload A fragments: af[tm][ks]  (full K)
    uint4 af[4][8];
#pragma unroll
    for (int tm = 0; tm < 4; ++tm) {
        int row = bm + mr * 64 + tm * 16 + l16;
        if (row >= M) row = M - 1;  // clamp: loads in-bounds, stores masked later
        const unsigned short* ap = A + (size_t)row * D + quad * 8;
#pragma unroll
        for (int ks = 0; ks < 8; ++ks)
            af[tm][ks] = *reinterpret_cast<const uint4*>(ap + ks * 32);
    }

    f32x4 acc[4][4];
#pragma unroll
    for (int tm = 0; tm < 4; ++tm)
#pragma unroll
        for (int tn = 0; tn < 4; ++tn) acc[tm][tn] = (f32x4){0.f, 0.f, 0.f, 0.f};

#pragma unroll
    for (int half = 0; half < 2; ++half) {
        // stage B half: 128 rows x 128 k (32 KB), coalesced 16B loads, swizzled
        {
            int c = t & 15;      // 16B chunk within 128-k row
            int r0 = t >> 4;     // 0..15
#pragma unroll
            for (int j = 0; j < 8; ++j) {
                int r = r0 + j * 16;
                uint4 v = *reinterpret_cast<const uint4*>(
                    Bt + (size_t)(bn + r) * D + half * 128 + c * 8);
                *reinterpret_cast<uint4*>(sm + SW2(r, c)) = v;
            }
        }
        __syncthreads();
#pragma unroll
        for (int ks = 0; ks < 4; ++ks) {
            int gks = half * 4 + ks;
            short8 b[4];
#pragma unroll
            for (int tn = 0; tn < 4; ++tn) {
                int n = nc * 64 + tn * 16 + l16;
                b[tn] = *reinterpret_cast<const short8*>(sm + SW2(n, ks * 4 + quad));
            }
#pragma unroll
            for (int tm = 0; tm < 4; ++tm) {
                short8 a = __builtin_bit_cast(short8, af[tm][gks]);
#pragma unroll
                for (int tn = 0; tn < 4; ++tn)
                    acc[tm][tn] = __builtin_amdgcn_mfma_f32_16x16x32_bf16(a, b[tn], acc[tm][tn], 0, 0, 0);
            }
        }
        __syncthreads();  // before restaging / epilogue reuse
    }

    uint8_t (*sC)[136] = reinterpret_cast<uint8_t (*)[136]>(sm);  // 17.4 KB fp8 tile
#pragma unroll
    for (int tm = 0; tm < 4; ++tm) {
        int rb = mr * 64 + tm * 16 + quad * 4;
#pragma unroll
        for (int tn = 0; tn < 4; ++tn) {
            int cc = nc * 64 + tn * 16 + l16;
#pragma unroll
            for (int r = 0; r < 4; ++r)
                sC[rb + r][cc] = f32_to_fp8(acc[tm][tn][r]);
        }
    }
    __syncthreads();

    // coalesced write: 128 rows x 8 chunks of 16B = 1024 chunks / 256 thr
#pragma unroll
    for (int it = 0; it < 4; ++it) {
        int idx = it * 256 + t;
        int r = idx >> 3, ch = idx & 7;
        int gr = bm + r;
        if (gr < M)
            *reinterpret_cast<uint4*>(Cb + (size_t)gr * D + bn + ch * 16) =
                *reinterpret_cast<const uint4*>(&sC[r][ch * 16]);
    }
}

// one wave per node: fp8 gather-aggregate + bias + LN + ReLU -> bf16.
// Edge metadata (row dword-offset, weight rsqrt(deg(src)+1)) staged
// cooperatively in LDS in ONE parallel step (lane j <-> edge j); main loop
// is pure 32-bit-addressed row gathers + cvt + fmac; di factored out.
__global__ __launch_bounds__(256) void k_agg(const uint8_t* __restrict__ hb,
                                             const int* __restrict__ cur,
                                             const int* __restrict__ ewi,
                                             const float* __restrict__ bias,
                                             const float* __restrict__ lnw,
                                             const float* __restrict__ lnb,
                                             unsigned short* __restrict__ out, int n) {
    __shared__ int2 lew[4][CAP];
    int wave = threadIdx.x >> 6, lane = threadIdx.x & 63;
    int node = blockIdx.x * 4 + wave;
    if (node >= n) return;
    int cdeg = cur[node];
    int cnt = min(cdeg, CAP);
    // cooperative stage: lane j handles edge j (wave-synchronous, no barrier)
    if (lane < cnt) {
        int s = ewi[node * CAP + lane];
        int2 p;
        p.x = s * 64;                                            // row offset in dwords
        p.y = __builtin_bit_cast(int, rsqrtf((float)(cur[s] + 1)));  // weight
        lew[wave][lane] = p;
    }
    __builtin_amdgcn_wave_barrier();

    float di = rsqrtf((float)(cdeg + 1));
    const uint32_t* hb32 = (const uint32_t*)hb;
    uint32_t rs = hb32[(uint32_t)node * 64 + lane];
    f32x4 acc = (f32x4){0.f, 0.f, 0.f, 0.f};   // Σ dinv[s]*x_s (di applied once)
    const int2* lep = lew[wave];
    int nq = cnt >> 2;

    int2 p0, p1, p2, p3;
    if (nq > 0) { p0 = lep[0]; p1 = lep[1]; p2 = lep[2]; p3 = lep[3]; }
    int q = 0;
#pragma unroll 1
    for (; q + 1 < nq; ++q) {
        int b4 = (q + 1) * 4;
        uint32_t r0 = hb32[(uint32_t)(p0.x + lane)];
        uint32_t r1 = hb32[(uint32_t)(p1.x + lane)];
        uint32_t r2 = hb32[(uint32_t)(p2.x + lane)];
        uint32_t r3 = hb32[(uint32_t)(p3.x + lane)];
        int2 n0 = lep[b4], n1 = lep[b4 + 1], n2 = lep[b4 + 2], n3 = lep[b4 + 3];
        acc += fp8x4_to_f32(r0) * __builtin_bit_cast(float, p0.y);
        acc += fp8x4_to_f32(r1) * __builtin_bit_cast(float, p1.y);
        acc += fp8x4_to_f32(r2) * __builtin_bit_cast(float, p2.y);
        acc += fp8x4_to_f32(r3) * __builtin_bit_cast(float, p3.y);
        p0 = n0; p1 = n1; p2 = n2; p3 = n3;
    }
    if (nq > 0) {
        uint32_t r0 = hb32[(uint32_t)(p0.x + lane)];
        uint32_t r1 = hb32[(uint32_t)(p1.x + lane)];
        uint32_t r2 = hb32[(uint32_t)(p2.x + lane)];
        uint32_t r3 = hb32[(uint32_t)(p3.x + lane)];
        acc += fp8x4_to_f32(r0) * __builtin_bit_cast(float, p0.y);
        acc += fp8x4_to_f32(r1) * __builtin_bit_cast(float, p1.y);
        acc += fp8x4_to_f32(r2) * __builtin_bit_cast(float, p2.y);
        acc += fp8x4_to_f32(r3) * __builtin_bit_cast(float, p3.y);
    }
    for (int e = nq * 4; e < cnt; ++e) {
        int2 p = lep[e];
        uint32_t r = hb32[(uint32_t)(p.x + lane)];
        acc += fp8x4_to_f32(r) * __builtin_bit_cast(float, p.y);
    }

    f32x4 self = fp8x4_to_f32(rs);
    f32x4 b4v = ((const f32x4*)bias)[lane];
    f32x4 v = self * (di * di) + acc * di + b4v;

    float s1 = v.x + v.y + v.z + v.w;
    float s2 = v.x * v.x + v.y * v.y + v.z * v.z + v.w * v.w;
#pragma unroll
    for (int o = 32; o > 0; o >>= 1) {
        s1 += __shfl_xor(s1, o, 64);
        s2 += __shfl_xor(s2, o, 64);
    }
    float mean = s1 * (1.0f / 256.0f);
    float var = s2 * (1.0f / 256.0f) - mean * mean;
    float inv = rsqrtf(var + 1e-5f);
    f32x4 w4 = ((const f32x4*)lnw)[lane];
    f32x4 lb = ((const f32x4*)lnb)[lane];
    float y0 = fmaxf((v.x - mean) * inv * w4.x + lb.x, 0.f);
    float y1 = fmaxf((v.y - mean) * inv * w4.y + lb.y, 0.f);
    float y2 = fmaxf((v.z - mean) * inv * w4.z + lb.z, 0.f);
    float y3 = fmaxf((v.w - mean) * inv * w4.w + lb.w, 0.f);
    uint2 w;
    w.x = (uint32_t)f2bf(y0) | ((uint32_t)f2bf(y1) << 16);
    w.y = (uint32_t)f2bf(y2) | ((uint32_t)f2bf(y3) << 16);
    *reinterpret_cast<uint2*>(out + (size_t)node * D + lane * 4) = w;
}

// one block per graph: mean-pool (batch sorted -> binary search) + linear
__global__ __launch_bounds__(256) void k_pool(const unsigned short* __restrict__ h,
                                              const int* __restrict__ batch,
                                              const float* __restrict__ linW,
                                              const float* __restrict__ linb,
                                              float* __restrict__ out,
                                              int nNodes) {
    int g = blockIdx.x, t = threadIdx.x;
    int lo = 0, hi = nNodes;
    while (lo < hi) { int m = (lo + hi) >> 1; if (batch[m] < g) lo = m + 1; else hi = m; }
    int lo2 = lo, hi2 = nNodes;
    while (lo2 < hi2) { int m = (lo2 + hi2) >> 1; if (batch[m] < g + 1) lo2 = m + 1; else hi2 = m; }
    float s0 = 0.f, s1 = 0.f, s2 = 0.f, s3 = 0.f;
    int i = lo;
    for (; i + 4 <= lo2; i += 4) {
        s0 += bf2f(h[(size_t)(i + 0) * D + t]);
        s1 += bf2f(h[(size_t)(i + 1) * D + t]);
        s2 += bf2f(h[(size_t)(i + 2) * D + t]);
        s3 += bf2f(h[(size_t)(i + 3) * D + t]);
    }
    for (; i < lo2; ++i) s0 += bf2f(h[(size_t)i * D + t]);
    float s = (s0 + s1) + (s2 + s3);
    float cnt = (float)(lo2 - lo);
    float pooled = s / fmaxf(cnt, 1.f);
    __shared__ float sp[256];
    __shared__ float red[4];
    sp[t] = pooled;
    __syncthreads();
    for (int c = 0; c < 10; ++c) {
        float v = sp[t] * linW[t * 10 + c];
#pragma unroll
        for (int o = 32; o > 0; o >>= 1) v += __shfl_xor(v, o, 64);
        if ((t & 63) == 0) red[t >> 6] = v;
        __syncthreads();
        if (t == 0) out[g * 10 + c] = red[0] + red[1] + red[2] + red[3] + linb[c];
        __syncthreads();
    }
}

extern "C" void kernel_launch(void* const* d_in, const int* in_sizes, int n_in,
                              void* d_out, int out_size, void* d_ws, size_t ws_size,
                              hipStream_t stream) {
    const float* x    = (const float*)d_in[0];
    const int*   ei   = (const int*)d_in[1];
    const int*   batch= (const int*)d_in[2];
    const float* W1   = (const float*)d_in[3];
    const float* b1   = (const float*)d_in[4];
    const float* W2   = (const float*)d_in[5];
    const float* b2   = (const float*)d_in[6];
    const float* ln1w = (const float*)d_in[7];
    const float* ln1b = (const float*)d_in[8];
    const float* ln2w = (const float*)d_in[9];
    const float* ln2b = (const float*)d_in[10];
    const float* linW = (const float*)d_in[11];
    const float* linb = (const float*)d_in[12];
    float* out = (float*)d_out;

    int nNodes  = in_sizes[0] / D;   // 50000
    int nEdges  = in_sizes[1] / 2;   // 800000
    int nGraphs = out_size / 10;     // 512

    const int* src = ei;
    const int* dst = ei + nEdges;

    char* ws = (char*)d_ws;
    size_t o = 0;
    auto alloc = [&](size_t bytes) -> char* {
        char* p = ws + o;
        o += (bytes + 511) & ~(size_t)511;
        return p;
    };
    unsigned short* xb = (unsigned short*)alloc((size_t)nNodes * D * 2);  // bf16 x / h2
    uint8_t* hW = (uint8_t*)alloc((size_t)nNodes * D);                    // fp8 gemm out
    unsigned short* h1 = (unsigned short*)alloc((size_t)nNodes * D * 2);  // bf16 LN out
    int* cur   = (int*)alloc((size_t)nNodes * 4);
    int* ewi   = (int*)alloc((size_t)nNodes * CAP * 4);  // padded src buckets
    unsigned short* Wt1 = (unsigned short*)alloc((size_t)D * D * 2);
    unsigned short* Wt2 = (unsigned short*)alloc((size_t)D * D * 2);
    (void)ws_size;

    int ge4 = (nEdges / 4 + 255) / 256;   // 782 (4 edges/thread)
    int n8 = nNodes * (D / 8);
    int nf2b = (n8 + 255) / 256;          // 6250
    int ngemm = ((nNodes + 127) / 128) * 2;  // 782

    // zero cur, then fused fill + x-cast + W-transpose (fill blocks first)
    hipMemsetAsync(cur, 0, (size_t)nNodes * 4, stream);
    k_prepfill<<<ge4 + nf2b + 512, 256, 0, stream>>>(src, dst, cur, ewi, nEdges,
                                                     x, xb, n8, W1, W2, Wt1, Wt2,
                                                     ge4, nf2b);
    // layer 1
    k_gemm<<<ngemm, 256, 0, stream>>>(xb, Wt1, hW, nNodes);
    k_agg<<<(nNodes + 3) / 4, 256, 0, stream>>>(hW, cur, ewi,
                                                b1, ln1w, ln1b, h1, nNodes);
    // layer 2 (reuse xb as h2)
    k_gemm<<<ngemm, 256, 0, stream>>>(h1, Wt2, hW, nNodes);
    k_agg<<<(nNodes + 3) / 4, 256, 0, stream>>>(hW, cur, ewi,
                                                b2, ln2w, ln2b, xb, nNodes);
    // pool + classifier
    k_pool<<<nGraphs, 256, 0, stream>>>(xb, batch, linW, linb, out, nNodes);
}

// Round 17
// 273.116 us; speedup vs baseline: 1.1765x; 1.1765x over previous
//
#include <hip/hip_runtime.h>
#include <hip/hip_fp8.h>
#include <stdint.h>

#define D 256
#define CAP 64  // bucket capacity per node (= wave width; Poisson(16) overflow ~impossible)

typedef __attribute__((ext_vector_type(8))) short short8;
typedef __attribute__((ext_vector_type(4))) float f32x4;

// swizzled LDS offset (in shorts) of 16B chunk c (0..15) within 128-k row n
#define SW2(n, c) (((n) << 7) + ((((c) ^ ((n) & 7))) << 3))

__device__ inline unsigned short f2bf(float f) {
    uint32_t u = __builtin_bit_cast(uint32_t, f);
    uint32_t r = (u + 0x7FFFu + ((u >> 16) & 1u)) >> 16;  // RNE
    return (unsigned short)r;
}

__device__ inline float bf2f(unsigned short b) {
    return __builtin_bit_cast(float, (uint32_t)b << 16);
}

// 4 packed OCP e4m3 -> 4 floats (HW cvt)
__device__ inline f32x4 fp8x4_to_f32(uint32_t v) {
    __hip_fp8x4_e4m3 a;
    a.__x = v;
    float4 f = (float4)a;
    return (f32x4){f.x, f.y, f.z, f.w};
}

__device__ inline uint8_t f32_to_fp8(float f) {
    __hip_fp8_e4m3 q(f);
    return (uint8_t)q.__x;
}

// fused prep: [0,nf2b) cast x->bf16; [nf2b,nf2b+512) W1,W2 transpose+cast;
// [nf2b+512, ...) zero cur
__global__ __launch_bounds__(256) void k_prep(const float* __restrict__ x,
                                              unsigned short* __restrict__ xb, int n8,
                                              const float* __restrict__ W1,
                                              const float* __restrict__ W2,
                                              unsigned short* __restrict__ Wt1,
                                              unsigned short* __restrict__ Wt2,
                                              int* __restrict__ cur,
                                              int nNodes, int nf2b) {
    int b = blockIdx.x, t = threadIdx.x;
    if (b < nf2b) {
        int i = b * 256 + t;
        if (i < n8) {
            f32x4 v0 = ((const f32x4*)x)[i * 2];
            f32x4 v1 = ((const f32x4*)x)[i * 2 + 1];
            short8 o;
            o[0] = (short)f2bf(v0.x); o[1] = (short)f2bf(v0.y);
            o[2] = (short)f2bf(v0.z); o[3] = (short)f2bf(v0.w);
            o[4] = (short)f2bf(v1.x); o[5] = (short)f2bf(v1.y);
            o[6] = (short)f2bf(v1.z); o[7] = (short)f2bf(v1.w);
            ((short8*)xb)[i] = o;
        }
    } else if (b < nf2b + 512) {
        int idx = (b - nf2b) * 256 + t;       // [0, 131072)
        int w = idx >> 16;                    // 0 -> W1, 1 -> W2
        int r = idx & 65535;
        int n = r >> 8, k = r & 255;
        const float* W = w ? W2 : W1;
        unsigned short* Wt = w ? Wt2 : Wt1;
        Wt[n * 256 + k] = f2bf(W[k * 256 + n]);
    } else {
        int i = (b - nf2b - 512) * 256 + t;
        if (i < nNodes) cur[i] = 0;
    }
}

// --- device bodies shared by fused + standalone kernels ---

// 128x128 tile gemm; B staged in LDS in TWO 128-k halves (32 KB), A in regs.
// 4 waves 2x2; per wave 4x4 MFMA frags. C written as OCP e4m3 fp8.
__device__ __forceinline__ void gemm_body(unsigned short* sm, int gid,
                                          const unsigned short* __restrict__ A,
                                          const unsigned short* __restrict__ Bt,
                                          uint8_t* __restrict__ Cb, int M) {
    int t = threadIdx.x;
    int wave = t >> 6, lane = t & 63;
    int quad = lane >> 4, l16 = lane & 15;
    int mr = wave >> 1, nc = wave & 1;
    int bm = (gid >> 1) * 128;
    int bn = (gid & 1) * 128;

    // preload A fragments: af[tm][ks]  (full K)
    uint4 af[4][8];
#pragma unroll
    for (int tm = 0; tm < 4; ++tm) {
        int row = bm + mr * 64 + tm * 16 + l16;
        if (row >= M) row = M - 1;  // clamp: loads in-bounds, stores masked later
        const unsigned short* ap = A + (size_t)row * D + quad * 8;
#pragma unroll
        for (int ks = 0; ks < 8; ++ks)
            af[tm][ks] = *reinterpret_cast<const uint4*>(ap + ks * 32);
    }

    f32x4 acc[4][4];
#pragma unroll
    for (int tm = 0; tm < 4; ++tm)
#pragma unroll
        for (int tn = 0; tn < 4; ++tn) acc[tm][tn] = (f32x4){0.f, 0.f, 0.f, 0.f};

#pragma unroll
    for (int half = 0; half < 2; ++half) {
        // stage B half: 128 rows x 128 k (32 KB), coalesced 16B loads, swizzled
        {
            int c = t & 15;      // 16B chunk within 128-k row
            int r0 = t >> 4;     // 0..15
#pragma unroll
            for (int j = 0; j < 8; ++j) {
                int r = r0 + j * 16;
                uint4 v = *reinterpret_cast<const uint4*>(
                    Bt + (size_t)(bn + r) * D + half * 128 + c * 8);
                *reinterpret_cast<uint4*>(sm + SW2(r, c)) = v;
            }
        }
        __syncthreads();
#pragma unroll
        for (int ks = 0; ks < 4; ++ks) {
            int gks = half * 4 + ks;
            short8 b[4];
#pragma unroll
            for (int tn = 0; tn < 4; ++tn) {
                int n = nc * 64 + tn * 16 + l16;
                b[tn] = *reinterpret_cast<const short8*>(sm + SW2(n, ks * 4 + quad));
            }
#pragma unroll
            for (int tm = 0; tm < 4; ++tm) {
                short8 a = __builtin_bit_cast(short8, af[tm][gks]);
#pragma unroll
                for (int tn = 0; tn < 4; ++tn)
                    acc[tm][tn] = __builtin_amdgcn_mfma_f32_16x16x32_bf16(a, b[tn], acc[tm][tn], 0, 0, 0);
            }
        }
        __syncthreads();  // before restaging / epilogue reuse
    }

    uint8_t (*sC)[136] = reinterpret_cast<uint8_t (*)[136]>(sm);  // 17.4 KB fp8 tile
#pragma unroll
    for (int tm = 0; tm < 4; ++tm) {
        int rb = mr * 64 + tm * 16 + quad * 4;
#pragma unroll
        for (int tn = 0; tn < 4; ++tn) {
            int cc = nc * 64 + tn * 16 + l16;
#pragma unroll
            for (int r = 0; r < 4; ++r)
                sC[rb + r][cc] = f32_to_fp8(acc[tm][tn][r]);
        }
    }
    __syncthreads();

    // coalesced write: 128 rows x 8 chunks of 16B = 1024 chunks / 256 thr
#pragma unroll
    for (int it = 0; it < 4; ++it) {
        int idx = it * 256 + t;
        int r = idx >> 3, ch = idx & 7;
        int gr = bm + r;
        if (gr < M)
            *reinterpret_cast<uint4*>(Cb + (size_t)gr * D + bn + ch * 16) =
                *reinterpret_cast<const uint4*>(&sC[r][ch * 16]);
    }
}

// 8 edges per thread (halves concurrent fill waves -> less atomic contention)
__device__ __forceinline__ void fill_body(int fid,
                                          const int* __restrict__ src,
                                          const int* __restrict__ dst,
                                          int* __restrict__ cur,
                                          int* __restrict__ ewi, int ne) {
    int i = (fid * 256 + threadIdx.x) * 8;
    if (i + 8 <= ne) {
        int4 sa = *reinterpret_cast<const int4*>(src + i);
        int4 sb = *reinterpret_cast<const int4*>(src + i + 4);
        int4 da = *reinterpret_cast<const int4*>(dst + i);
        int4 db = *reinterpret_cast<const int4*>(dst + i + 4);
        int p;
        p = atomicAdd(&cur[da.x], 1); if (p < CAP) ewi[da.x * CAP + p] = sa.x;
        p = atomicAdd(&cur[da.y], 1); if (p < CAP) ewi[da.y * CAP + p] = sa.y;
        p = atomicAdd(&cur[da.z], 1); if (p < CAP) ewi[da.z * CAP + p] = sa.z;
        p = atomicAdd(&cur[da.w], 1); if (p < CAP) ewi[da.w * CAP + p] = sa.w;
        p = atomicAdd(&cur[db.x], 1); if (p < CAP) ewi[db.x * CAP + p] = sb.x;
        p = atomicAdd(&cur[db.y], 1); if (p < CAP) ewi[db.y * CAP + p] = sb.y;
        p = atomicAdd(&cur[db.z], 1); if (p < CAP) ewi[db.z * CAP + p] = sb.z;
        p = atomicAdd(&cur[db.w], 1); if (p < CAP) ewi[db.w * CAP + p] = sb.w;
    } else {
        for (int j = i; j < ne; ++j) {
            int s = src[j], d = dst[j];
            int p = atomicAdd(&cur[d], 1);
            if (p < CAP) ewi[d * CAP + p] = s;
        }
    }
}

// fused: layer-1 gemm + bucket fill, 2 gemm : 1 fill (independent work).
// Requires ngemm == 2*nfill (782 == 2*391).
__global__ __launch_bounds__(256, 2) void k_gemmfill(const unsigned short* __restrict__ A,
                                                     const unsigned short* __restrict__ Bt,
                                                     uint8_t* __restrict__ Cb, int M,
                                                     const int* __restrict__ src,
                                                     const int* __restrict__ dst,
                                                     int* __restrict__ cur,
                                                     int* __restrict__ ewi, int ne) {
    __shared__ unsigned short sm[16384];  // 32 KB
    int b = blockIdx.x;
    int q = b / 3, r = b % 3;
    if (r == 2) fill_body(q, src, dst, cur, ewi, ne);
    else        gemm_body(sm, q * 2 + r, A, Bt, Cb, M);
}

// standalone gemm (layer 2)
__global__ __launch_bounds__(256, 2) void k_gemm(const unsigned short* __restrict__ A,
                                                 const unsigned short* __restrict__ Bt,
                                                 uint8_t* __restrict__ Cb, int M) {
    __shared__ unsigned short sm[16384];
    gemm_body(sm, blockIdx.x, A, Bt, Cb, M);
}

// one wave per node: fp8 gather-aggregate + bias + LN + ReLU -> bf16.
// Edge metadata (row dword-offset, weight rsqrt(deg(src)+1)) staged
// cooperatively in LDS in ONE parallel step (lane j <-> edge j); main loop
// is pure 32-bit-addressed row gathers + cvt + fmac; di factored out.
__global__ __launch_bounds__(256) void k_agg(const uint8_t* __restrict__ hb,
                                             const int* __restrict__ cur,
                                             const int* __restrict__ ewi,
                                             const float* __restrict__ bias,
                                             const float* __restrict__ lnw,
                                             const float* __restrict__ lnb,
                                             unsigned short* __restrict__ out, int n) {
    __shared__ int2 lew[4][CAP];
    int wave = threadIdx.x >> 6, lane = threadIdx.x & 63;
    int node = blockIdx.x * 4 + wave;
    if (node >= n) return;
    int cdeg = cur[node];
    int cnt = min(cdeg, CAP);
    // cooperative stage: lane j handles edge j (wave-synchronous, no barrier)
    if (lane < cnt) {
        int s = ewi[node * CAP + lane];
        int2 p;
        p.x = s * 64;                                            // row offset in dwords
        p.y = __builtin_bit_cast(int, rsqrtf((float)(cur[s] + 1)));  // weight
        lew[wave][lane] = p;
    }
    __builtin_amdgcn_wave_barrier();

    float di = rsqrtf((float)(cdeg + 1));
    const uint32_t* hb32 = (const uint32_t*)hb;
    uint32_t rs = hb32[(uint32_t)node * 64 + lane];
    f32x4 acc = (f32x4){0.f, 0.f, 0.f, 0.f};   // Σ dinv[s]*x_s (di applied once)
    const int2* lep = lew[wave];
    int nq = cnt >> 2;

    int2 p0, p1, p2, p3;
    if (nq > 0) { p0 = lep[0]; p1 = lep[1]; p2 = lep[2]; p3 = lep[3]; }
    int q = 0;
#pragma unroll 1
    for (; q + 1 < nq; ++q) {
        int b4 = (q + 1) * 4;
        uint32_t r0 = hb32[(uint32_t)(p0.x + lane)];
        uint32_t r1 = hb32[(uint32_t)(p1.x + lane)];
        uint32_t r2 = hb32[(uint32_t)(p2.x + lane)];
        uint32_t r3 = hb32[(uint32_t)(p3.x + lane)];
        int2 n0 = lep[b4], n1 = lep[b4 + 1], n2 = lep[b4 + 2], n3 = lep[b4 + 3];
        acc += fp8x4_to_f32(r0) * __builtin_bit_cast(float, p0.y);
        acc += fp8x4_to_f32(r1) * __builtin_bit_cast(float, p1.y);
        acc += fp8x4_to_f32(r2) * __builtin_bit_cast(float, p2.y);
        acc += fp8x4_to_f32(r3) * __builtin_bit_cast(float, p3.y);
        p0 = n0; p1 = n1; p2 = n2; p3 = n3;
    }
    if (nq > 0) {
        uint32_t r0 = hb32[(uint32_t)(p0.x + lane)];
        uint32_t r1 = hb32[(uint32_t)(p1.x + lane)];
        uint32_t r2 = hb32[(uint32_t)(p2.x + lane)];
        uint32_t r3 = hb32[(uint32_t)(p3.x + lane)];
        acc += fp8x4_to_f32(r0) * __builtin_bit_cast(float, p0.y);
        acc += fp8x4_to_f32(r1) * __builtin_bit_cast(float, p1.y);
        acc += fp8x4_to_f32(r2) * __builtin_bit_cast(float, p2.y);
        acc += fp8x4_to_f32(r3) * __builtin_bit_cast(float, p3.y);
    }
    for (int e = nq * 4; e < cnt; ++e) {
        int2 p = lep[e];
        uint32_t r = hb32[(uint32_t)(p.x + lane)];
        acc += fp8x4_to_f32(r) * __builtin_bit_cast(float, p.y);
    }

    f32x4 self = fp8x4_to_f32(rs);
    f32x4 b4v = ((const f32x4*)bias)[lane];
    f32x4 v = self * (di * di) + acc * di + b4v;

    float s1 = v.x + v.y + v.z + v.w;
    float s2 = v.x * v.x + v.y * v.y + v.z * v.z + v.w * v.w;
#pragma unroll
    for (int o = 32; o > 0; o >>= 1) {
        s1 += __shfl_xor(s1, o, 64);
        s2 += __shfl_xor(s2, o, 64);
    }
    float mean = s1 * (1.0f / 256.0f);
    float var = s2 * (1.0f / 256.0f) - mean * mean;
    float inv = rsqrtf(var + 1e-5f);
    f32x4 w4 = ((const f32x4*)lnw)[lane];
    f32x4 lb = ((const f32x4*)lnb)[lane];
    float y0 = fmaxf((v.x - mean) * inv * w4.x + lb.x, 0.f);
    float y1 = fmaxf((v.y - mean) * inv * w4.y + lb.y, 0.f);
    float y2 = fmaxf((v.z - mean) * inv * w4.z + lb.z, 0.f);
    float y3 = fmaxf((v.w - mean) * inv * w4.w + lb.w, 0.f);
    uint2 w;
    w.x = (uint32_t)f2bf(y0) | ((uint32_t)f2bf(y1) << 16);
    w.y = (uint32_t)f2bf(y2) | ((uint32_t)f2bf(y3) << 16);
    *reinterpret_cast<uint2*>(out + (size_t)node * D + lane * 4) = w;
}

// one block per graph: mean-pool (batch sorted -> binary search) + linear
__global__ __launch_bounds__(256) void k_pool(const unsigned short* __restrict__ h,
                                              const int* __restrict__ batch,
                                              const float* __restrict__ linW,
                                              const float* __restrict__ linb,
                                              float* __restrict__ out,
                                              int nNodes) {
    int g = blockIdx.x, t = threadIdx.x;
    int lo = 0, hi = nNodes;
    while (lo < hi) { int m = (lo + hi) >> 1; if (batch[m] < g) lo = m + 1; else hi = m; }
    int lo2 = lo, hi2 = nNodes;
    while (lo2 < hi2) { int m = (lo2 + hi2) >> 1; if (batch[m] < g + 1) lo2 = m + 1; else hi2 = m; }
    float s0 = 0.f, s1 = 0.f, s2 = 0.f, s3 = 0.f;
    int i = lo;
    for (; i + 4 <= lo2; i += 4) {
        s0 += bf2f(h[(size_t)(i + 0) * D + t]);
        s1 += bf2f(h[(size_t)(i + 1) * D + t]);
        s2 += bf2f(h[(size_t)(i + 2) * D + t]);
        s3 += bf2f(h[(size_t)(i + 3) * D + t]);
    }
    for (; i < lo2; ++i) s0 += bf2f(h[(size_t)i * D + t]);
    float s = (s0 + s1) + (s2 + s3);
    float cnt = (float)(lo2 - lo);
    float pooled = s / fmaxf(cnt, 1.f);
    __shared__ float sp[256];
    __shared__ float red[4];
    sp[t] = pooled;
    __syncthreads();
    for (int c = 0; c < 10; ++c) {
        float v = sp[t] * linW[t * 10 + c];
#pragma unroll
        for (int o = 32; o > 0; o >>= 1) v += __shfl_xor(v, o, 64);
        if ((t & 63) == 0) red[t >> 6] = v;
        __syncthreads();
        if (t == 0) out[g * 10 + c] = red[0] + red[1] + red[2] + red[3] + linb[c];
        __syncthreads();
    }
}

extern "C" void kernel_launch(void* const* d_in, const int* in_sizes, int n_in,
                              void* d_out, int out_size, void* d_ws, size_t ws_size,
                              hipStream_t stream) {
    const float* x    = (const float*)d_in[0];
    const int*   ei   = (const int*)d_in[1];
    const int*   batch= (const int*)d_in[2];
    const float* W1   = (const float*)d_in[3];
    const float* b1   = (const float*)d_in[4];
    const float* W2   = (const float*)d_in[5];
    const float* b2   = (const float*)d_in[6];
    const float* ln1w = (const float*)d_in[7];
    const float* ln1b = (const float*)d_in[8];
    const float* ln2w = (const float*)d_in[9];
    const float* ln2b = (const float*)d_in[10];
    const float* linW = (const float*)d_in[11];
    const float* linb = (const float*)d_in[12];
    float* out = (float*)d_out;

    int nNodes  = in_sizes[0] / D;   // 50000
    int nEdges  = in_sizes[1] / 2;   // 800000
    int nGraphs = out_size / 10;     // 512

    const int* src = ei;
    const int* dst = ei + nEdges;

    char* ws = (char*)d_ws;
    size_t o = 0;
    auto alloc = [&](size_t bytes) -> char* {
        char* p = ws + o;
        o += (bytes + 511) & ~(size_t)511;
        return p;
    };
    unsigned short* xb = (unsigned short*)alloc((size_t)nNodes * D * 2);  // bf16 x / h2
    uint8_t* hW = (uint8_t*)alloc((size_t)nNodes * D);                    // fp8 gemm out
    unsigned short* h1 = (unsigned short*)alloc((size_t)nNodes * D * 2);  // bf16 LN out
    int* cur   = (int*)alloc((size_t)nNodes * 4);
    int* ewi   = (int*)alloc((size_t)nNodes * CAP * 4);  // padded src buckets
    unsigned short* Wt1 = (unsigned short*)alloc((size_t)D * D * 2);
    unsigned short* Wt2 = (unsigned short*)alloc((size_t)D * D * 2);
    (void)ws_size;

    int gn = (nNodes + 255) / 256;        // 196
    int ge8 = (nEdges / 8 + 255) / 256;   // 391 (8 edges/thread)
    int n8 = nNodes * (D / 8);
    int nf2b = (n8 + 255) / 256;          // 6250
    int ngemm = ((nNodes + 127) / 128) * 2;  // 782 == 2*ge8

    // prep: cast x, transpose W1/W2, zero cur
    k_prep<<<nf2b + 512 + gn, 256, 0, stream>>>(x, xb, n8, W1, W2, Wt1, Wt2,
                                                cur, nNodes, nf2b);
    // layer-1 gemm + bucket fill (independent; 2 gemm : 1 fill interleave)
    k_gemmfill<<<ngemm + ge8, 256, 0, stream>>>(xb, Wt1, hW, nNodes,
                                                src, dst, cur, ewi, nEdges);
    // layer 1 aggregate + LN + ReLU
    k_agg<<<(nNodes + 3) / 4, 256, 0, stream>>>(hW, cur, ewi,
                                                b1, ln1w, ln1b, h1, nNodes);
    // layer 2 (reuse xb as h2)
    k_gemm<<<ngemm, 256, 0, stream>>>(h1, Wt2, hW, nNodes);
    k_agg<<<(nNodes + 3) / 4, 256, 0, stream>>>(hW, cur, ewi,
                                                b2, ln2w, ln2b, xb, nNodes);
    // pool + classifier
    k_pool<<<nGraphs, 256, 0, stream>>>(xb, batch, linW, linb, out, nNodes);
}

// Round 18
// 268.449 us; speedup vs baseline: 1.1970x; 1.0174x over previous
//
#include <hip/hip_runtime.h>
#include <hip/hip_fp8.h>
#include <stdint.h>

#define D 256
#define CAP 64  // bucket capacity per node (= wave width; Poisson(16) overflow ~impossible)

typedef __attribute__((ext_vector_type(8))) short short8;
typedef __attribute__((ext_vector_type(4))) float f32x4;

// swizzled LDS offset (in shorts) of 16B chunk c (0..15) within 128-k row n
#define SW2(n, c) (((n) << 7) + ((((c) ^ ((n) & 7))) << 3))

__device__ inline unsigned short f2bf(float f) {
    uint32_t u = __builtin_bit_cast(uint32_t, f);
    uint32_t r = (u + 0x7FFFu + ((u >> 16) & 1u)) >> 16;  // RNE
    return (unsigned short)r;
}

__device__ inline float bf2f(unsigned short b) {
    return __builtin_bit_cast(float, (uint32_t)b << 16);
}

// 4 packed OCP e4m3 -> 4 floats (HW cvt)
__device__ inline f32x4 fp8x4_to_f32(uint32_t v) {
    __hip_fp8x4_e4m3 a;
    a.__x = v;
    float4 f = (float4)a;
    return (f32x4){f.x, f.y, f.z, f.w};
}

__device__ inline uint8_t f32_to_fp8(float f) {
    __hip_fp8_e4m3 q(f);
    return (uint8_t)q.__x;
}

// fused prep: [0,nf2b) cast x->bf16; [nf2b,nf2b+512) W1,W2 transpose+cast;
// [nf2b+512, ...) zero cur
__global__ __launch_bounds__(256) void k_prep(const float* __restrict__ x,
                                              unsigned short* __restrict__ xb, int n8,
                                              const float* __restrict__ W1,
                                              const float* __restrict__ W2,
                                              unsigned short* __restrict__ Wt1,
                                              unsigned short* __restrict__ Wt2,
                                              int* __restrict__ cur,
                                              int nNodes, int nf2b) {
    int b = blockIdx.x, t = threadIdx.x;
    if (b < nf2b) {
        int i = b * 256 + t;
        if (i < n8) {
            f32x4 v0 = ((const f32x4*)x)[i * 2];
            f32x4 v1 = ((const f32x4*)x)[i * 2 + 1];
            short8 o;
            o[0] = (short)f2bf(v0.x); o[1] = (short)f2bf(v0.y);
            o[2] = (short)f2bf(v0.z); o[3] = (short)f2bf(v0.w);
            o[4] = (short)f2bf(v1.x); o[5] = (short)f2bf(v1.y);
            o[6] = (short)f2bf(v1.z); o[7] = (short)f2bf(v1.w);
            ((short8*)xb)[i] = o;
        }
    } else if (b < nf2b + 512) {
        int idx = (b - nf2b) * 256 + t;       // [0, 131072)
        int w = idx >> 16;                    // 0 -> W1, 1 -> W2
        int r = idx & 65535;
        int n = r >> 8, k = r & 255;
        const float* W = w ? W2 : W1;
        unsigned short* Wt = w ? Wt2 : Wt1;
        Wt[n * 256 + k] = f2bf(W[k * 256 + n]);
    } else {
        int i = (b - nf2b - 512) * 256 + t;
        if (i < nNodes) cur[i] = 0;
    }
}

// --- device bodies shared by fused + standalone kernels ---

// 128x128 tile gemm; B staged in LDS in TWO 128-k halves (32 KB), A in regs.
// 4 waves 2x2; per wave 4x4 MFMA frags. C written as OCP e4m3 fp8.
__device__ __forceinline__ void gemm_body(unsigned short* sm, int gid,
                                          const unsigned short* __restrict__ A,
                                          const unsigned short* __restrict__ Bt,
                                          uint8_t* __restrict__ Cb, int M) {
    int t = threadIdx.x;
    int wave = t >> 6, lane = t & 63;
    int quad = lane >> 4, l16 = lane & 15;
    int mr = wave >> 1, nc = wave & 1;
    int bm = (gid >> 1) * 128;
    int bn = (gid & 1) * 128;

    // preload A fragments: af[tm][ks]  (full K)
    uint4 af[4][8];
#pragma unroll
    for (int tm = 0; tm < 4; ++tm) {
        int row = bm + mr * 64 + tm * 16 + l16;
        if (row >= M) row = M - 1;  // clamp: loads in-bounds, stores masked later
        const unsigned short* ap = A + (size_t)row * D + quad * 8;
#pragma unroll
        for (int ks = 0; ks < 8; ++ks)
            af[tm][ks] = *reinterpret_cast<const uint4*>(ap + ks * 32);
    }

    f32x4 acc[4][4];
#pragma unroll
    for (int tm = 0; tm < 4; ++tm)
#pragma unroll
        for (int tn = 0; tn < 4; ++tn) acc[tm][tn] = (f32x4){0.f, 0.f, 0.f, 0.f};

#pragma unroll
    for (int half = 0; half < 2; ++half) {
        // stage B half: 128 rows x 128 k (32 KB), coalesced 16B loads, swizzled
        {
            int c = t & 15;      // 16B chunk within 128-k row
            int r0 = t >> 4;     // 0..15
#pragma unroll
            for (int j = 0; j < 8; ++j) {
                int r = r0 + j * 16;
                uint4 v = *reinterpret_cast<const uint4*>(
                    Bt + (size_t)(bn + r) * D + half * 128 + c * 8);
                *reinterpret_cast<uint4*>(sm + SW2(r, c)) = v;
            }
        }
        __syncthreads();
#pragma unroll
        for (int ks = 0; ks < 4; ++ks) {
            int gks = half * 4 + ks;
            short8 b[4];
#pragma unroll
            for (int tn = 0; tn < 4; ++tn) {
                int n = nc * 64 + tn * 16 + l16;
                b[tn] = *reinterpret_cast<const short8*>(sm + SW2(n, ks * 4 + quad));
            }
#pragma unroll
            for (int tm = 0; tm < 4; ++tm) {
                short8 a = __builtin_bit_cast(short8, af[tm][gks]);
#pragma unroll
                for (int tn = 0; tn < 4; ++tn)
                    acc[tm][tn] = __builtin_amdgcn_mfma_f32_16x16x32_bf16(a, b[tn], acc[tm][tn], 0, 0, 0);
            }
        }
        __syncthreads();  // before restaging / epilogue reuse
    }

    uint8_t (*sC)[136] = reinterpret_cast<uint8_t (*)[136]>(sm);  // 17.4 KB fp8 tile
#pragma unroll
    for (int tm = 0; tm < 4; ++tm) {
        int rb = mr * 64 + tm * 16 + quad * 4;
#pragma unroll
        for (int tn = 0; tn < 4; ++tn) {
            int cc = nc * 64 + tn * 16 + l16;
#pragma unroll
            for (int r = 0; r < 4; ++r)
                sC[rb + r][cc] = f32_to_fp8(acc[tm][tn][r]);
        }
    }
    __syncthreads();

    // coalesced write: 128 rows x 8 chunks of 16B = 1024 chunks / 256 thr
#pragma unroll
    for (int it = 0; it < 4; ++it) {
        int idx = it * 256 + t;
        int r = idx >> 3, ch = idx & 7;
        int gr = bm + r;
        if (gr < M)
            *reinterpret_cast<uint4*>(Cb + (size_t)gr * D + bn + ch * 16) =
                *reinterpret_cast<const uint4*>(&sC[r][ch * 16]);
    }
}

// 4 edges/thread; all 4 atomics issued before any dependent store (2x RMW ILP)
__device__ __forceinline__ void fill_body(int fid,
                                          const int* __restrict__ src,
                                          const int* __restrict__ dst,
                                          int* __restrict__ cur,
                                          int* __restrict__ ewi, int ne) {
    int i = (fid * 256 + threadIdx.x) * 4;
    if (i + 4 <= ne) {
        int4 s4 = *reinterpret_cast<const int4*>(src + i);
        int4 d4 = *reinterpret_cast<const int4*>(dst + i);
        int p0 = atomicAdd(&cur[d4.x], 1);
        int p1 = atomicAdd(&cur[d4.y], 1);
        int p2 = atomicAdd(&cur[d4.z], 1);
        int p3 = atomicAdd(&cur[d4.w], 1);
        if (p0 < CAP) ewi[d4.x * CAP + p0] = s4.x;
        if (p1 < CAP) ewi[d4.y * CAP + p1] = s4.y;
        if (p2 < CAP) ewi[d4.z * CAP + p2] = s4.z;
        if (p3 < CAP) ewi[d4.w * CAP + p3] = s4.w;
    } else {
        for (int j = i; j < ne; ++j) {
            int s = src[j], d = dst[j];
            int p = atomicAdd(&cur[d], 1);
            if (p < CAP) ewi[d * CAP + p] = s;
        }
    }
}

// fused: layer-1 gemm + bucket fill, alternating blocks (independent work)
__global__ __launch_bounds__(256, 2) void k_gemmfill(const unsigned short* __restrict__ A,
                                                     const unsigned short* __restrict__ Bt,
                                                     uint8_t* __restrict__ Cb, int M,
                                                     const int* __restrict__ src,
                                                     const int* __restrict__ dst,
                                                     int* __restrict__ cur,
                                                     int* __restrict__ ewi, int ne,
                                                     int NI, int ngemm) {
    __shared__ unsigned short sm[16384];  // 32 KB
    int b = blockIdx.x;
    if (b < 2 * NI) {
        if (b & 1) fill_body(b >> 1, src, dst, cur, ewi, ne);
        else       gemm_body(sm, b >> 1, A, Bt, Cb, M);
    } else {
        int r = b - 2 * NI;
        if (ngemm > NI) gemm_body(sm, NI + r, A, Bt, Cb, M);
        else            fill_body(NI + r, src, dst, cur, ewi, ne);
    }
}

// standalone gemm (layer 2)
__global__ __launch_bounds__(256, 2) void k_gemm(const unsigned short* __restrict__ A,
                                                 const unsigned short* __restrict__ Bt,
                                                 uint8_t* __restrict__ Cb, int M) {
    __shared__ unsigned short sm[16384];
    gemm_body(sm, blockIdx.x, A, Bt, Cb, M);
}

// one wave per node: fp8 gather-aggregate + bias + LN + ReLU -> bf16.
// Edge metadata (row dword-offset, weight rsqrt(deg(src)+1)) staged
// cooperatively in LDS in ONE parallel step (lane j <-> edge j); main loop
// is pure 32-bit-addressed row gathers + cvt + fmac; di factored out.
__global__ __launch_bounds__(256) void k_agg(const uint8_t* __restrict__ hb,
                                             const int* __restrict__ cur,
                                             const int* __restrict__ ewi,
                                             const float* __restrict__ bias,
                                             const float* __restrict__ lnw,
                                             const float* __restrict__ lnb,
                                             unsigned short* __restrict__ out, int n) {
    __shared__ int2 lew[4][CAP];
    int wave = threadIdx.x >> 6, lane = threadIdx.x & 63;
    int node = blockIdx.x * 4 + wave;
    if (node >= n) return;
    int cdeg = cur[node];
    int cnt = min(cdeg, CAP);
    // cooperative stage: lane j handles edge j (wave-synchronous, no barrier)
    if (lane < cnt) {
        int s = ewi[node * CAP + lane];
        int2 p;
        p.x = s * 64;                                            // row offset in dwords
        p.y = __builtin_bit_cast(int, rsqrtf((float)(cur[s] + 1)));  // weight
        lew[wave][lane] = p;
    }
    __builtin_amdgcn_wave_barrier();

    float di = rsqrtf((float)(cdeg + 1));
    const uint32_t* hb32 = (const uint32_t*)hb;
    uint32_t rs = hb32[(uint32_t)node * 64 + lane];
    f32x4 acc = (f32x4){0.f, 0.f, 0.f, 0.f};   // Σ dinv[s]*x_s (di applied once)
    const int2* lep = lew[wave];
    int nq = cnt >> 2;

    int2 p0, p1, p2, p3;
    if (nq > 0) { p0 = lep[0]; p1 = lep[1]; p2 = lep[2]; p3 = lep[3]; }
    int q = 0;
#pragma unroll 1
    for (; q + 1 < nq; ++q) {
        int b4 = (q + 1) * 4;
        uint32_t r0 = hb32[(uint32_t)(p0.x + lane)];
        uint32_t r1 = hb32[(uint32_t)(p1.x + lane)];
        uint32_t r2 = hb32[(uint32_t)(p2.x + lane)];
        uint32_t r3 = hb32[(uint32_t)(p3.x + lane)];
        int2 n0 = lep[b4], n1 = lep[b4 + 1], n2 = lep[b4 + 2], n3 = lep[b4 + 3];
        acc += fp8x4_to_f32(r0) * __builtin_bit_cast(float, p0.y);
        acc += fp8x4_to_f32(r1) * __builtin_bit_cast(float, p1.y);
        acc += fp8x4_to_f32(r2) * __builtin_bit_cast(float, p2.y);
        acc += fp8x4_to_f32(r3) * __builtin_bit_cast(float, p3.y);
        p0 = n0; p1 = n1; p2 = n2; p3 = n3;
    }
    if (nq > 0) {
        uint32_t r0 = hb32[(uint32_t)(p0.x + lane)];
        uint32_t r1 = hb32[(uint32_t)(p1.x + lane)];
        uint32_t r2 = hb32[(uint32_t)(p2.x + lane)];
        uint32_t r3 = hb32[(uint32_t)(p3.x + lane)];
        acc += fp8x4_to_f32(r0) * __builtin_bit_cast(float, p0.y);
        acc += fp8x4_to_f32(r1) * __builtin_bit_cast(float, p1.y);
        acc += fp8x4_to_f32(r2) * __builtin_bit_cast(float, p2.y);
        acc += fp8x4_to_f32(r3) * __builtin_bit_cast(float, p3.y);
    }
    for (int e = nq * 4; e < cnt; ++e) {
        int2 p = lep[e];
        uint32_t r = hb32[(uint32_t)(p.x + lane)];
        acc += fp8x4_to_f32(r) * __builtin_bit_cast(float, p.y);
    }

    f32x4 self = fp8x4_to_f32(rs);
    f32x4 b4v = ((const f32x4*)bias)[lane];
    f32x4 v = self * (di * di) + acc * di + b4v;

    float s1 = v.x + v.y + v.z + v.w;
    float s2 = v.x * v.x + v.y * v.y + v.z * v.z + v.w * v.w;
#pragma unroll
    for (int o = 32; o > 0; o >>= 1) {
        s1 += __shfl_xor(s1, o, 64);
        s2 += __shfl_xor(s2, o, 64);
    }
    float mean = s1 * (1.0f / 256.0f);
    float var = s2 * (1.0f / 256.0f) - mean * mean;
    float inv = rsqrtf(var + 1e-5f);
    f32x4 w4 = ((const f32x4*)lnw)[lane];
    f32x4 lb = ((const f32x4*)lnb)[lane];
    float y0 = fmaxf((v.x - mean) * inv * w4.x + lb.x, 0.f);
    float y1 = fmaxf((v.y - mean) * inv * w4.y + lb.y, 0.f);
    float y2 = fmaxf((v.z - mean) * inv * w4.z + lb.z, 0.f);
    float y3 = fmaxf((v.w - mean) * inv * w4.w + lb.w, 0.f);
    uint2 w;
    w.x = (uint32_t)f2bf(y0) | ((uint32_t)f2bf(y1) << 16);
    w.y = (uint32_t)f2bf(y2) | ((uint32_t)f2bf(y3) << 16);
    *reinterpret_cast<uint2*>(out + (size_t)node * D + lane * 4) = w;
}

// one block per graph: mean-pool (batch sorted -> binary search) + linear
__global__ __launch_bounds__(256) void k_pool(const unsigned short* __restrict__ h,
                                              const int* __restrict__ batch,
                                              const float* __restrict__ linW,
                                              const float* __restrict__ linb,
                                              float* __restrict__ out,
                                              int nNodes) {
    int g = blockIdx.x, t = threadIdx.x;
    int lo = 0, hi = nNodes;
    while (lo < hi) { int m = (lo + hi) >> 1; if (batch[m] < g) lo = m + 1; else hi = m; }
    int lo2 = lo, hi2 = nNodes;
    while (lo2 < hi2) { int m = (lo2 + hi2) >> 1; if (batch[m] < g + 1) lo2 = m + 1; else hi2 = m; }
    float s0 = 0.f, s1 = 0.f, s2 = 0.f, s3 = 0.f;
    int i = lo;
    for (; i + 4 <= lo2; i += 4) {
        s0 += bf2f(h[(size_t)(i + 0) * D + t]);
        s1 += bf2f(h[(size_t)(i + 1) * D + t]);
        s2 += bf2f(h[(size_t)(i + 2) * D + t]);
        s3 += bf2f(h[(size_t)(i + 3) * D + t]);
    }
    for (; i < lo2; ++i) s0 += bf2f(h[(size_t)i * D + t]);
    float s = (s0 + s1) + (s2 + s3);
    float cnt = (float)(lo2 - lo);
    float pooled = s / fmaxf(cnt, 1.f);
    __shared__ float sp[256];
    __shared__ float red[4];
    sp[t] = pooled;
    __syncthreads();
    for (int c = 0; c < 10; ++c) {
        float v = sp[t] * linW[t * 10 + c];
#pragma unroll
        for (int o = 32; o > 0; o >>= 1) v += __shfl_xor(v, o, 64);
        if ((t & 63) == 0) red[t >> 6] = v;
        __syncthreads();
        if (t == 0) out[g * 10 + c] = red[0] + red[1] + red[2] + red[3] + linb[c];
        __syncthreads();
    }
}

extern "C" void kernel_launch(void* const* d_in, const int* in_sizes, int n_in,
                              void* d_out, int out_size, void* d_ws, size_t ws_size,
                              hipStream_t stream) {
    const float* x    = (const float*)d_in[0];
    const int*   ei   = (const int*)d_in[1];
    const int*   batch= (const int*)d_in[2];
    const float* W1   = (const float*)d_in[3];
    const float* b1   = (const float*)d_in[4];
    const float* W2   = (const float*)d_in[5];
    const float* b2   = (const float*)d_in[6];
    const float* ln1w = (const float*)d_in[7];
    const float* ln1b = (const float*)d_in[8];
    const float* ln2w = (const float*)d_in[9];
    const float* ln2b = (const float*)d_in[10];
    const float* linW = (const float*)d_in[11];
    const float* linb = (const float*)d_in[12];
    float* out = (float*)d_out;

    int nNodes  = in_sizes[0] / D;   // 50000
    int nEdges  = in_sizes[1] / 2;   // 800000
    int nGraphs = out_size / 10;     // 512

    const int* src = ei;
    const int* dst = ei + nEdges;

    char* ws = (char*)d_ws;
    size_t o = 0;
    auto alloc = [&](size_t bytes) -> char* {
        char* p = ws + o;
        o += (bytes + 511) & ~(size_t)511;
        return p;
    };
    unsigned short* xb = (unsigned short*)alloc((size_t)nNodes * D * 2);  // bf16 x / h2
    uint8_t* hW = (uint8_t*)alloc((size_t)nNodes * D);                    // fp8 gemm out
    unsigned short* h1 = (unsigned short*)alloc((size_t)nNodes * D * 2);  // bf16 LN out
    int* cur   = (int*)alloc((size_t)nNodes * 4);
    int* ewi   = (int*)alloc((size_t)nNodes * CAP * 4);  // padded src buckets
    unsigned short* Wt1 = (unsigned short*)alloc((size_t)D * D * 2);
    unsigned short* Wt2 = (unsigned short*)alloc((size_t)D * D * 2);
    (void)ws_size;

    int gn = (nNodes + 255) / 256;        // 196
    int ge4 = (nEdges / 4 + 255) / 256;   // 782 (4 edges/thread)
    int n8 = nNodes * (D / 8);
    int nf2b = (n8 + 255) / 256;          // 6250
    int ngemm = ((nNodes + 127) / 128) * 2;  // 782
    int NI = min(ngemm, ge4);

    // prep: cast x, transpose W1/W2, zero cur
    k_prep<<<nf2b + 512 + gn, 256, 0, stream>>>(x, xb, n8, W1, W2, Wt1, Wt2,
                                                cur, nNodes, nf2b);
    // layer-1 gemm + bucket fill (independent; interleaved blocks)
    k_gemmfill<<<ngemm + ge4, 256, 0, stream>>>(xb, Wt1, hW, nNodes,
                                                src, dst, cur, ewi, nEdges,
                                                NI, ngemm);
    // layer 1 aggregate + LN + ReLU
    k_agg<<<(nNodes + 3) / 4, 256, 0, stream>>>(hW, cur, ewi,
                                                b1, ln1w, ln1b, h1, nNodes);
    // layer 2 (reuse xb as h2)
    k_gemm<<<ngemm, 256, 0, stream>>>(h1, Wt2, hW, nNodes);
    k_agg<<<(nNodes + 3) / 4, 256, 0, stream>>>(hW, cur, ewi,
                                                b2, ln2w, ln2b, xb, nNodes);
    // pool + classifier
    k_pool<<<nGraphs, 256, 0, stream>>>(xb, batch, linW, linb, out, nNodes);
}